// Round 4
// baseline (439.601 us; speedup 1.0000x reference)
//
#include <hip/hip_runtime.h>

// Problem constants: b=16, c=128, groups=8, h=w=64 -> n=4096
#define NB   16
#define NC   128
#define NPOS 4096

typedef short bf16x8 __attribute__((ext_vector_type(8)));   // 8 bf16 (4 VGPRs)
typedef float f32x4  __attribute__((ext_vector_type(4)));
typedef float f32x16 __attribute__((ext_vector_type(16)));
typedef unsigned int u32x4 __attribute__((ext_vector_type(4)));

// softmax scale folded into q at QKV time: log2(e)/sqrt(128)
#define SCF 0.12751743075095855f

static __device__ __forceinline__ unsigned short f2bf(float f) {
    unsigned int u = __builtin_bit_cast(unsigned int, f);
    u += 0x7FFFu + ((u >> 16) & 1u);   // round-to-nearest-even
    return (unsigned short)(u >> 16);
}

// pack two floats -> bf16x2 dword (truncating; exp2-arg pre-biased to center)
static __device__ __forceinline__ unsigned int pkbf(float hi, float lo) {
    return __builtin_amdgcn_perm(__builtin_bit_cast(unsigned int, hi),
                                 __builtin_bit_cast(unsigned int, lo), 0x07060302u);
}

// ---------------- K0: fp32 -> bf16 weight conversion (64 blocks x 256) ----------------
__global__ void wconv_kernel(const float* __restrict__ wq, const float* __restrict__ wk,
                             const float* __restrict__ wv, const float* __restrict__ wf,
                             unsigned short* __restrict__ oq, unsigned short* __restrict__ ok,
                             unsigned short* __restrict__ ov, unsigned short* __restrict__ of) {
    int i = blockIdx.x * 256 + threadIdx.x;
    oq[i] = f2bf(wq[i]); ok[i] = f2bf(wk[i]); ov[i] = f2bf(wv[i]); of[i] = f2bf(wf[i]);
}

// ---------------- K1: GroupNorm stats, one block per (b,g), 128 blocks ----------------
__global__ void gnstat_kernel(const float* __restrict__ x, float* __restrict__ mean,
                              float* __restrict__ rstd) {
    int bg = blockIdx.x;
    const float* p = x + (size_t)bg * 65536;
    int t = threadIdx.x;
    float s = 0.f, q = 0.f;
    for (int it = 0; it < 64; ++it) {
        f32x4 v = *(const f32x4*)(p + it * 1024 + t * 4);
        s += v[0] + v[1] + v[2] + v[3];
        q += v[0] * v[0] + v[1] * v[1] + v[2] * v[2] + v[3] * v[3];
    }
    for (int m = 1; m < 64; m <<= 1) { s += __shfl_xor(s, m); q += __shfl_xor(q, m); }
    __shared__ float ls[4], lq[4];
    int w = t >> 6;
    if ((t & 63) == 0) { ls[w] = s; lq[w] = q; }
    __syncthreads();
    if (t == 0) {
        s = ls[0] + ls[1] + ls[2] + ls[3];
        q = lq[0] + lq[1] + lq[2] + lq[3];
        float mu  = s * (1.0f / 65536.0f);
        float var = q * (1.0f / 65536.0f) - mu * mu;
        mean[bg] = mu;
        rstd[bg] = rsqrtf(var + 1e-5f);
    }
}

// ---------------- K2: GN-apply + QKV GEMMs (grid 64 x 16, 256 thr) ----------------
// q is pre-scaled by SCF (softmax scale fold).
__global__ __launch_bounds__(256) void qkv_kernel(
    const float* __restrict__ x, const float* __restrict__ gnw, const float* __restrict__ gnb,
    const float* __restrict__ mean, const float* __restrict__ rstd,
    const unsigned short* __restrict__ wqb, const unsigned short* __restrict__ wkb,
    const unsigned short* __restrict__ wvb,
    const float* __restrict__ bq, const float* __restrict__ bk, const float* __restrict__ bv,
    unsigned short* __restrict__ qT, unsigned short* __restrict__ kT, unsigned short* __restrict__ vv) {
    __shared__ __attribute__((aligned(16))) unsigned short xn[64 * 136];  // [i][c], stride 136
    const int b = blockIdx.y, i0 = blockIdx.x * 64;
    const int t = threadIdx.x;
    {
        int iL = (t & 15) * 4;
        int cb = (t >> 4) * 2;
        for (int cg = 0; cg < 4; ++cg) {
            int c = cg * 32 + cb;
            int g = c >> 4;
            float mu = mean[b * 8 + g], rs = rstd[b * 8 + g];
            float ga0 = gnw[c] * rs,     be0 = gnb[c]     - mu * ga0;
            float ga1 = gnw[c + 1] * rs, be1 = gnb[c + 1] - mu * ga1;
            const float* p0 = x + ((size_t)(b * NC + c)) * NPOS + i0 + iL;
            f32x4 v0 = *(const f32x4*)p0;
            f32x4 v1 = *(const f32x4*)(p0 + NPOS);
            for (int e = 0; e < 4; ++e) {
                unsigned int u = (unsigned)f2bf(v0[e] * ga0 + be0) |
                                 ((unsigned)f2bf(v1[e] * ga1 + be1) << 16);
                *(unsigned int*)&xn[(iL + e) * 136 + c] = u;
            }
        }
    }
    __syncthreads();

    const int lane = t & 63, w = t >> 6, quad = lane >> 4, li = lane & 15;

    bf16x8 ax[4];
    for (int kc = 0; kc < 4; ++kc)
        ax[kc] = *(const bf16x8*)&xn[(w * 16 + li) * 136 + kc * 32 + quad * 8];
    for (int wt = 0; wt < 2; ++wt) {
        const unsigned short* W = wt ? wkb : wqb;
        const float* bias = wt ? bk : bq;
        unsigned short* dst = wt ? kT : qT;
        const float osc = wt ? 1.0f : SCF;
        for (int nt = 0; nt < 8; ++nt) {
            f32x4 d = {0.f, 0.f, 0.f, 0.f};
            for (int kc = 0; kc < 4; ++kc) {
                bf16x8 bw = *(const bf16x8*)&W[(nt * 16 + li) * 128 + kc * 32 + quad * 8];
                d = __builtin_amdgcn_mfma_f32_16x16x32_bf16(ax[kc], bw, d, 0, 0, 0);
            }
            float bb = bias[nt * 16 + li];
            size_t base = ((size_t)b * NPOS + i0 + w * 16 + quad * 4) * NC + nt * 16 + li;
            for (int rr = 0; rr < 4; ++rr)
                dst[base + (size_t)rr * NC] = f2bf((d[rr] + bb) * osc);
        }
    }

    bf16x8 av[2][4];
    for (int mt = 0; mt < 2; ++mt)
        for (int kc = 0; kc < 4; ++kc)
            av[mt][kc] = *(const bf16x8*)&wvb[((w * 2 + mt) * 16 + li) * 128 + kc * 32 + quad * 8];
    for (int nt = 0; nt < 4; ++nt) {
        bf16x8 bx[4];
        for (int kc = 0; kc < 4; ++kc)
            bx[kc] = *(const bf16x8*)&xn[(nt * 16 + li) * 136 + kc * 32 + quad * 8];
        for (int mt = 0; mt < 2; ++mt) {
            f32x4 d = {0.f, 0.f, 0.f, 0.f};
            for (int kc = 0; kc < 4; ++kc)
                d = __builtin_amdgcn_mfma_f32_16x16x32_bf16(av[mt][kc], bx[kc], d, 0, 0, 0);
            int o0 = (w * 2 + mt) * 16 + quad * 4;
            for (int rr = 0; rr < 4; ++rr) {
                float val = d[rr] + bv[o0 + rr];
                vv[((size_t)(b * NC + o0 + rr)) * NPOS + i0 + nt * 16 + li] = f2bf(val);
            }
        }
    }
}

// ---------------- K3: flash attention, 32x32x16 MFMA, reg-prefetch pipeline ----------------
// grid (16 b, 64 i-tiles), 128 thr = 2 waves x 32 q-rows. j-tile = 64. 4 blocks/CU.
// S^T = K Q^T (A=K from LDS, B=Q regs): col = i = il -> per-lane scalar softmax state.
// Global loads for tile jt+1 overlap compute of tile jt (regs -> LDS at iter top).
__global__ __launch_bounds__(128, 2) void flash_kernel(
    const unsigned short* __restrict__ qT, const unsigned short* __restrict__ kT,
    const unsigned short* __restrict__ vv, unsigned short* __restrict__ oT) {
    __shared__ __attribute__((aligned(16))) unsigned short kt[64 * 128];   // [j][c] swizzled
    __shared__ __attribute__((aligned(16))) unsigned short vt[128 * 64];   // [c][j] swizzled
    const int b = blockIdx.x;
    const int t = threadIdx.x, lane = t & 63, w = t >> 6;
    const int il = lane & 31, h = lane >> 5;
    const int iw = blockIdx.y * 64 + w * 32;    // this wave's 32 q-rows

    // Q B-fragments (q pre-scaled by SCF), resident all 64 iters
    bf16x8 qb[8];
    for (int kc = 0; kc < 8; ++kc)
        qb[kc] = *(const bf16x8*)&qT[((size_t)b * NPOS + iw + il) * NC + kc * 16 + h * 8];

    float mrow = -1e30f, lrow = 0.f;
    f32x16 acc[4];   // acc[ct]: O^T rows c = 32ct + (r&3)+8(r>>2)+4h, col i = il
    for (int ct = 0; ct < 4; ++ct)
        for (int r = 0; r < 16; ++r) acc[ct][r] = 0.f;

    // ---- staging maps (per lane) ----
    // K: row r = w*32 + (l&31)  (r&7 == l&7), logical chunks lc = (l>>5)*8 + m (m=0..7 of 16)
    // V: row c = w*64 + (l&63)  (c&7 == l&7), logical chunks lc = m (m=0..7 of 8)
    const int kr = w * 32 + (lane & 31);
    const int vc = w * 64 + lane;
    const unsigned short* kg = &kT[((size_t)b * NPOS + kr) * NC + (lane >> 5) * 64];
    const unsigned short* vg = &vv[((size_t)(b * NC + vc)) * NPOS];
    unsigned short* kd = &kt[kr * 128];
    unsigned short* vd = &vt[vc * 64];
    const int x7 = lane & 7;

    bf16x8 kreg[8], vreg[8];
    #pragma unroll
    for (int m = 0; m < 8; ++m) {           // prologue: tile 0
        kreg[m] = *(const bf16x8*)(kg + m * 8);
        vreg[m] = *(const bf16x8*)(vg + m * 8);
    }

    for (int jt = 0; jt < 64; ++jt) {
        __syncthreads();                    // all waves done reading previous tile
        #pragma unroll
        for (int m = 0; m < 8; ++m) {
            *(bf16x8*)(kd + ((((lane >> 5) * 8 + m) ^ x7) << 3)) = kreg[m];
            *(bf16x8*)(vd + ((m ^ x7) << 3))                     = vreg[m];
        }
        __syncthreads();
        if (jt < 63) {                      // prefetch next tile; overlaps compute below
            const unsigned short* kgn = kg + (size_t)(jt + 1) * 64 * NC;
            const unsigned short* vgn = vg + (size_t)(jt + 1) * 64;
            #pragma unroll
            for (int m = 0; m < 8; ++m) {
                kreg[m] = *(const bf16x8*)(kgn + m * 8);
                vreg[m] = *(const bf16x8*)(vgn + m * 8);
            }
        }

        // S^T tiles: st0 = j 0..31, st1 = j 32..63 ; col = i = il
        f32x16 st0, st1;
        for (int r = 0; r < 16; ++r) { st0[r] = 0.f; st1[r] = 0.f; }
        #pragma unroll
        for (int kc = 0; kc < 8; ++kc) {
            bf16x8 a0 = *(const bf16x8*)&kt[il * 128 + (((kc * 2 + h) ^ (il & 7)) << 3)];
            bf16x8 a1 = *(const bf16x8*)&kt[(32 + il) * 128 + (((kc * 2 + h) ^ (il & 7)) << 3)];
            st0 = __builtin_amdgcn_mfma_f32_32x32x16_bf16(a0, qb[kc], st0, 0, 0, 0);
            st1 = __builtin_amdgcn_mfma_f32_32x32x16_bf16(a1, qb[kc], st1, 0, 0, 0);
        }

        // online softmax: per-lane scalar state (this lane's column i = il)
        float mx = st0[0];
        #pragma unroll
        for (int r = 1; r < 16; ++r) mx = fmaxf(mx, st0[r]);
        #pragma unroll
        for (int r = 0; r < 16; ++r) mx = fmaxf(mx, st1[r]);
        mx = fmaxf(mx, __shfl_xor(mx, 32));
        if (__any(mx > mrow)) {             // wave-uniform rescale, usually skipped
            float mn = fmaxf(mrow, mx);
            float alpha = __builtin_amdgcn_exp2f(mrow - mn);
            mrow = mn;
            lrow *= alpha;
            #pragma unroll
            for (int ct = 0; ct < 4; ++ct)
                #pragma unroll
                for (int r = 0; r < 16; ++r) acc[ct][r] *= alpha;
        }
        // mc = mrow - log2(1+2^-9): centers pkbf truncation (cancels in final ratio)
        float mc = mrow - 0.0028150156f;

        float p0[16], p1[16];
        float rs = 0.f;
        #pragma unroll
        for (int r = 0; r < 16; ++r) {
            p0[r] = __builtin_amdgcn_exp2f(st0[r] - mc);
            p1[r] = __builtin_amdgcn_exp2f(st1[r] - mc);
            rs += p0[r] + p1[r];
        }
        rs += __shfl_xor(rs, 32);
        lrow += rs;

        // Build P^T B-frags in-register (half-wave exchange via shfl_xor 32)
        bf16x8 pfrag[4];
        #pragma unroll
        for (int hf = 0; hf < 2; ++hf) {
            const float* pp = hf ? p1 : p0;
            #pragma unroll
            for (int c2 = 0; c2 < 2; ++c2) {
                int rb = c2 * 8;
                unsigned int A0 = pkbf(pp[rb + 1], pp[rb + 0]);
                unsigned int A1 = pkbf(pp[rb + 3], pp[rb + 2]);
                unsigned int B0 = pkbf(pp[rb + 5], pp[rb + 4]);
                unsigned int B1 = pkbf(pp[rb + 7], pp[rb + 6]);
                unsigned int s0 = h ? A0 : B0, s1 = h ? A1 : B1;   // what partner needs
                unsigned int r0 = __shfl_xor(s0, 32), r1 = __shfl_xor(s1, 32);
                u32x4 f;
                f[0] = h ? r0 : A0; f[1] = h ? r1 : A1;
                f[2] = h ? B0 : r0; f[3] = h ? B1 : r1;
                pfrag[hf * 2 + c2] = __builtin_bit_cast(bf16x8, f);
            }
        }

        // O^T += V^T P^T
        #pragma unroll
        for (int ct = 0; ct < 4; ++ct) {
            int cr = ct * 32 + il;
            #pragma unroll
            for (int kc2 = 0; kc2 < 4; ++kc2) {
                bf16x8 av = *(const bf16x8*)&vt[cr * 64 + (((kc2 * 2 + h) ^ (cr & 7)) << 3)];
                acc[ct] = __builtin_amdgcn_mfma_f32_32x32x16_bf16(av, pfrag[kc2], acc[ct], 0, 0, 0);
            }
        }
    }

    float inv = __builtin_amdgcn_rcpf(lrow);
    unsigned short* orow = &oT[((size_t)b * NPOS + iw + il) * NC];
    #pragma unroll
    for (int ct = 0; ct < 4; ++ct)
        #pragma unroll
        for (int r = 0; r < 16; r += 2) {
            int c = ct * 32 + (r & 3) + 8 * (r >> 2) + 4 * h;
            *(unsigned int*)&orow[c] = pkbf(acc[ct][r + 1] * inv, acc[ct][r] * inv);
        }
}

// ---------------- K4: out = wf @ o + bf + x  (grid 64 x 16, 256 thr) ----------------
__global__ __launch_bounds__(256) void proj_kernel(
    const unsigned short* __restrict__ oT, const unsigned short* __restrict__ wfb,
    const float* __restrict__ bf_, const float* __restrict__ x, float* __restrict__ out) {
    const int b = blockIdx.y, i0 = blockIdx.x * 64;
    const int t = threadIdx.x, lane = t & 63, w = t >> 6, quad = lane >> 4, li = lane & 15;
    bf16x8 aw[2][4];
    for (int mt = 0; mt < 2; ++mt)
        for (int kc = 0; kc < 4; ++kc)
            aw[mt][kc] = *(const bf16x8*)&wfb[((w * 2 + mt) * 16 + li) * 128 + kc * 32 + quad * 8];
    for (int nt = 0; nt < 4; ++nt) {
        bf16x8 bo[4];
        for (int kc = 0; kc < 4; ++kc)
            bo[kc] = *(const bf16x8*)&oT[((size_t)b * NPOS + i0 + nt * 16 + li) * NC + kc * 32 + quad * 8];
        for (int mt = 0; mt < 2; ++mt) {
            f32x4 d = {0.f, 0.f, 0.f, 0.f};
            for (int kc = 0; kc < 4; ++kc)
                d = __builtin_amdgcn_mfma_f32_16x16x32_bf16(aw[mt][kc], bo[kc], d, 0, 0, 0);
            int o0 = (w * 2 + mt) * 16 + quad * 4;
            for (int rr = 0; rr < 4; ++rr) {
                size_t idx = ((size_t)(b * NC + o0 + rr)) * NPOS + i0 + nt * 16 + li;
                out[idx] = d[rr] + bf_[o0 + rr] + x[idx];
            }
        }
    }
}

extern "C" void kernel_launch(void* const* d_in, const int* in_sizes, int n_in,
                              void* d_out, int out_size, void* d_ws, size_t ws_size,
                              hipStream_t stream) {
    const float* x   = (const float*)d_in[0];
    const float* gnw = (const float*)d_in[1];
    const float* gnb = (const float*)d_in[2];
    const float* wq  = (const float*)d_in[3];
    const float* bq  = (const float*)d_in[4];
    const float* wk  = (const float*)d_in[5];
    const float* bk  = (const float*)d_in[6];
    const float* wv  = (const float*)d_in[7];
    const float* bv  = (const float*)d_in[8];
    const float* wf  = (const float*)d_in[9];
    const float* bf_ = (const float*)d_in[10];
    float* out = (float*)d_out;

    char* ws = (char*)d_ws;
    float* mean = (float*)(ws + 0);
    float* rstd = (float*)(ws + 512);
    unsigned short* wqb = (unsigned short*)(ws + 1024);
    unsigned short* wkb = wqb + 16384;
    unsigned short* wvb = wkb + 16384;
    unsigned short* wfb = wvb + 16384;
    unsigned short* qT  = (unsigned short*)(ws + 132096);          // [b][n][c] bf16 (SCF-scaled)
    unsigned short* kT  = qT + (size_t)NB * NPOS * NC;             // [b][n][c]
    unsigned short* vv  = kT + (size_t)NB * NPOS * NC;             // [b][c][n]
    unsigned short* oT  = vv + (size_t)NB * NPOS * NC;             // [b][n][c]

    wconv_kernel<<<64, 256, 0, stream>>>(wq, wk, wv, wf, wqb, wkb, wvb, wfb);
    gnstat_kernel<<<128, 256, 0, stream>>>(x, mean, rstd);
    dim3 g(64, 16);
    qkv_kernel<<<g, 256, 0, stream>>>(x, gnw, gnb, mean, rstd, wqb, wkb, wvb, bq, bk, bv, qT, kT, vv);
    dim3 gf(16, 64);
    flash_kernel<<<gf, 128, 0, stream>>>(qT, kT, vv, oT);
    proj_kernel<<<g, 256, 0, stream>>>(oT, wfb, bf_, x, out);
}

// Round 6
// 404.628 us; speedup vs baseline: 1.0864x; 1.0864x over previous
//
#include <hip/hip_runtime.h>

// Problem constants: b=16, c=128, groups=8, h=w=64 -> n=4096
#define NB   16
#define NC   128
#define NPOS 4096

typedef short bf16x8 __attribute__((ext_vector_type(8)));   // 8 bf16 (4 VGPRs)
typedef float f32x4  __attribute__((ext_vector_type(4)));
typedef float f32x16 __attribute__((ext_vector_type(16)));
typedef unsigned int u32x4 __attribute__((ext_vector_type(4)));

// softmax scale folded into q at QKV time: log2(e)/sqrt(128)
#define SCF 0.12751743075095855f

static __device__ __forceinline__ unsigned short f2bf(float f) {
    unsigned int u = __builtin_bit_cast(unsigned int, f);
    u += 0x7FFFu + ((u >> 16) & 1u);   // round-to-nearest-even
    return (unsigned short)(u >> 16);
}

// pack two floats -> bf16x2 dword (truncating; exp2-arg pre-biased to center)
static __device__ __forceinline__ unsigned int pkbf(float hi, float lo) {
    return __builtin_amdgcn_perm(__builtin_bit_cast(unsigned int, hi),
                                 __builtin_bit_cast(unsigned int, lo), 0x07060302u);
}

// ---------------- K0: fp32 -> bf16 weight conversion (64 blocks x 256) ----------------
__global__ void wconv_kernel(const float* __restrict__ wq, const float* __restrict__ wk,
                             const float* __restrict__ wv, const float* __restrict__ wf,
                             unsigned short* __restrict__ oq, unsigned short* __restrict__ ok,
                             unsigned short* __restrict__ ov, unsigned short* __restrict__ of) {
    int i = blockIdx.x * 256 + threadIdx.x;
    oq[i] = f2bf(wq[i]); ok[i] = f2bf(wk[i]); ov[i] = f2bf(wv[i]); of[i] = f2bf(wf[i]);
}

// ---------------- K1: GroupNorm stats, one block per (b,g), 128 blocks ----------------
__global__ void gnstat_kernel(const float* __restrict__ x, float* __restrict__ mean,
                              float* __restrict__ rstd) {
    int bg = blockIdx.x;
    const float* p = x + (size_t)bg * 65536;
    int t = threadIdx.x;
    float s = 0.f, q = 0.f;
    for (int it = 0; it < 64; ++it) {
        f32x4 v = *(const f32x4*)(p + it * 1024 + t * 4);
        s += v[0] + v[1] + v[2] + v[3];
        q += v[0] * v[0] + v[1] * v[1] + v[2] * v[2] + v[3] * v[3];
    }
    for (int m = 1; m < 64; m <<= 1) { s += __shfl_xor(s, m); q += __shfl_xor(q, m); }
    __shared__ float ls[4], lq[4];
    int w = t >> 6;
    if ((t & 63) == 0) { ls[w] = s; lq[w] = q; }
    __syncthreads();
    if (t == 0) {
        s = ls[0] + ls[1] + ls[2] + ls[3];
        q = lq[0] + lq[1] + lq[2] + lq[3];
        float mu  = s * (1.0f / 65536.0f);
        float var = q * (1.0f / 65536.0f) - mu * mu;
        mean[bg] = mu;
        rstd[bg] = rsqrtf(var + 1e-5f);
    }
}

// ---------------- K2: GN-apply + QKV GEMMs (grid 64 x 16, 256 thr) ----------------
// q pre-scaled by SCF. Outputs:
//   qT [b][n][c] row-major
//   Kf frag-linear: [b][jt][jtile*8+kc][lane=h*32+il][e] , elem K[jt*64+jtile*32+il][kc*16+h*8+e]
//   Vf frag-linear: [b][jt][ct*4+kc2][lane=h*32+il][e]   , elem V[c=ct*32+il][jt*64+kc2*16+h*8+e]
// Epilogues bounce through XOR-swizzled LDS so every global store is a coalesced b128.
// Each tile is 8192 elems; 256 threads cover 32 elems (4 x bf16x8) each.
__global__ __launch_bounds__(256) void qkv_kernel(
    const float* __restrict__ x, const float* __restrict__ gnw, const float* __restrict__ gnb,
    const float* __restrict__ mean, const float* __restrict__ rstd,
    const unsigned short* __restrict__ wqb, const unsigned short* __restrict__ wkb,
    const unsigned short* __restrict__ wvb,
    const float* __restrict__ bq, const float* __restrict__ bk, const float* __restrict__ bv,
    unsigned short* __restrict__ qT, unsigned short* __restrict__ Kf, unsigned short* __restrict__ Vf) {
    __shared__ __attribute__((aligned(16))) unsigned short xn[64 * 136];  // [i][c], stride 136
    __shared__ __attribute__((aligned(16))) unsigned short bnc[64 * 128]; // bounce (8192 elems)
    const int b = blockIdx.y, i0 = blockIdx.x * 64, jt = blockIdx.x;
    const int t = threadIdx.x;
    {
        int iL = (t & 15) * 4;
        int cb = (t >> 4) * 2;
        for (int cg = 0; cg < 4; ++cg) {
            int c = cg * 32 + cb;
            int g = c >> 4;
            float mu = mean[b * 8 + g], rs = rstd[b * 8 + g];
            float ga0 = gnw[c] * rs,     be0 = gnb[c]     - mu * ga0;
            float ga1 = gnw[c + 1] * rs, be1 = gnb[c + 1] - mu * ga1;
            const float* p0 = x + ((size_t)(b * NC + c)) * NPOS + i0 + iL;
            f32x4 v0 = *(const f32x4*)p0;
            f32x4 v1 = *(const f32x4*)(p0 + NPOS);
            for (int e = 0; e < 4; ++e) {
                unsigned int u = (unsigned)f2bf(v0[e] * ga0 + be0) |
                                 ((unsigned)f2bf(v1[e] * ga1 + be1) << 16);
                *(unsigned int*)&xn[(iL + e) * 136 + c] = u;
            }
        }
    }
    __syncthreads();

    const int lane = t & 63, w = t >> 6, quad = lane >> 4, li = lane & 15;

    bf16x8 ax[4];
    for (int kc = 0; kc < 4; ++kc)
        ax[kc] = *(const bf16x8*)&xn[(w * 16 + li) * 136 + kc * 32 + quad * 8];

    // ---- q and k GEMMs; D[i][o], i = w*16+quad*4+rr, o = nt*16+li
    for (int wt = 0; wt < 2; ++wt) {
        const unsigned short* W = wt ? wkb : wqb;
        const float* bias = wt ? bk : bq;
        const float osc = wt ? 1.0f : SCF;
        for (int nt = 0; nt < 8; ++nt) {
            f32x4 d = {0.f, 0.f, 0.f, 0.f};
            for (int kc = 0; kc < 4; ++kc) {
                bf16x8 bw = *(const bf16x8*)&W[(nt * 16 + li) * 128 + kc * 32 + quad * 8];
                d = __builtin_amdgcn_mfma_f32_16x16x32_bf16(ax[kc], bw, d, 0, 0, 0);
            }
            float bb = bias[nt * 16 + li];
            int o = nt * 16 + li;
            for (int rr = 0; rr < 4; ++rr) {
                int i = w * 16 + quad * 4 + rr;
                bnc[i * 128 + (((o >> 3) ^ (i & 7)) << 3) + (o & 7)] = f2bf((d[rr] + bb) * osc);
            }
        }
        __syncthreads();
        if (wt == 0) {
            // qT row-major: thread t covers flat [t*32, t*32+32): i = t>>2, c = (t&3)*32 + s*8..
            unsigned short* dst = qT + ((size_t)b * NPOS + i0) * NC + t * 32;
            int i = t >> 2;
            for (int s = 0; s < 4; ++s) {
                int cc = (t & 3) * 4 + s;
                *(bf16x8*)(dst + s * 8) = *(const bf16x8*)&bnc[i * 128 + ((cc ^ (i & 7)) << 3)];
            }
        } else {
            // Kf: thread t covers flat [t*32, ...): F = t>>4 = jtile*8+kc ; L = (t*4+s)&63
            unsigned short* dst = Kf + ((size_t)(b * 64 + jt)) * 8192 + t * 32;
            int F = t >> 4, jtile = F >> 3, kc = F & 7;
            for (int s = 0; s < 4; ++s) {
                int L = (t * 4 + s) & 63;
                int i = jtile * 32 + (L & 31);
                int cc = kc * 2 + (L >> 5);
                *(bf16x8*)(dst + s * 8) = *(const bf16x8*)&bnc[i * 128 + ((cc ^ (i & 7)) << 3)];
            }
        }
        __syncthreads();
    }

    // ---- v GEMM: D[o=c][i=j], c = (w*2+mt)*16+quad*4+rr, j = nt*16+li
    bf16x8 av[2][4];
    for (int mt = 0; mt < 2; ++mt)
        for (int kc = 0; kc < 4; ++kc)
            av[mt][kc] = *(const bf16x8*)&wvb[((w * 2 + mt) * 16 + li) * 128 + kc * 32 + quad * 8];
    for (int nt = 0; nt < 4; ++nt) {
        bf16x8 bx[4];
        for (int kc = 0; kc < 4; ++kc)
            bx[kc] = *(const bf16x8*)&xn[(nt * 16 + li) * 136 + kc * 32 + quad * 8];
        for (int mt = 0; mt < 2; ++mt) {
            f32x4 d = {0.f, 0.f, 0.f, 0.f};
            for (int kc = 0; kc < 4; ++kc)
                d = __builtin_amdgcn_mfma_f32_16x16x32_bf16(av[mt][kc], bx[kc], d, 0, 0, 0);
            int o0 = (w * 2 + mt) * 16 + quad * 4;
            int j = nt * 16 + li;
            for (int rr = 0; rr < 4; ++rr) {
                int c = o0 + rr;
                bnc[c * 64 + (((j >> 3) ^ (c & 7)) << 3) + (j & 7)] = f2bf(d[rr] + bv[c]);
            }
        }
    }
    __syncthreads();
    {
        // Vf: thread t covers flat [t*32, ...): F = t>>4 = ct*4+kc2 ; L = (t*4+s)&63
        unsigned short* dst = Vf + ((size_t)(b * 64 + jt)) * 8192 + t * 32;
        int F = t >> 4, ct = F >> 2, kc2 = F & 3;
        for (int s = 0; s < 4; ++s) {
            int L = (t * 4 + s) & 63;
            int c = ct * 32 + (L & 31);
            int jc = kc2 * 2 + (L >> 5);
            *(bf16x8*)(dst + s * 8) = *(const bf16x8*)&bnc[c * 64 + ((jc ^ (c & 7)) << 3)];
        }
    }
}

// ---------------- K3: flash attention — barrier-free, LDS-free ----------------
// grid 512 x 128 thr = 2 independent waves/block; each wave: 64 q-rows, all j.
// All K/V fragments load directly from frag-linear global (1 KB coalesced per frag).
// b swizzled so each XCD works on 2 batches (K+V working set 4 MB = per-XCD L2).
__global__ __launch_bounds__(128, 1) void flash_kernel(
    const unsigned short* __restrict__ qT, const unsigned short* __restrict__ Kf,
    const unsigned short* __restrict__ Vf, unsigned short* __restrict__ oT) {
    const int idx = blockIdx.x;
    const int b = (idx & 7) * 2 + ((idx >> 3) & 1);
    const int r = idx >> 4;                       // 0..31
    const int t = threadIdx.x, lane = t & 63, w = t >> 6;
    const int il = lane & 31, h = lane >> 5;
    const int iw = r * 128 + w * 64;              // this wave's 64 q-rows

    // Q B-frags for both i-groups (q pre-scaled by SCF): 64 VGPRs, resident
    bf16x8 qb[2][8];
    #pragma unroll
    for (int ig = 0; ig < 2; ++ig)
        #pragma unroll
        for (int kc = 0; kc < 8; ++kc)
            qb[ig][kc] = *(const bf16x8*)&qT[((size_t)b * NPOS + iw + ig * 32 + il) * NC + kc * 16 + h * 8];

    float mr[2] = {-1e30f, -1e30f}, lr[2] = {0.f, 0.f};
    f32x16 acc[2][4];
    #pragma unroll
    for (int ig = 0; ig < 2; ++ig)
        #pragma unroll
        for (int ct = 0; ct < 4; ++ct)
            #pragma unroll
            for (int q = 0; q < 16; ++q) acc[ig][ct][q] = 0.f;

    const unsigned short* kp = Kf + ((size_t)b * 64) * 8192 + lane * 8;
    const unsigned short* vp = Vf + ((size_t)b * 64) * 8192 + lane * 8;

    for (int jt = 0; jt < 64; ++jt) {
        // 16 K frags + 16 V frags, each one coalesced 1 KB wave-load
        bf16x8 kf[2][8], vf[4][4];
        #pragma unroll
        for (int jti = 0; jti < 2; ++jti)
            #pragma unroll
            for (int kc = 0; kc < 8; ++kc)
                kf[jti][kc] = *(const bf16x8*)(kp + (jti * 8 + kc) * 512);
        #pragma unroll
        for (int ct = 0; ct < 4; ++ct)
            #pragma unroll
            for (int kc2 = 0; kc2 < 4; ++kc2)
                vf[ct][kc2] = *(const bf16x8*)(vp + (ct * 4 + kc2) * 512);
        kp += 8192;
        vp += 8192;

        // S^T: st[ig*2+jti] ; col i = il, rows j = jti*32 + C-rows
        f32x16 st[4];
        #pragma unroll
        for (int u = 0; u < 4; ++u)
            #pragma unroll
            for (int q = 0; q < 16; ++q) st[u][q] = 0.f;
        #pragma unroll
        for (int kc = 0; kc < 8; ++kc) {
            st[0] = __builtin_amdgcn_mfma_f32_32x32x16_bf16(kf[0][kc], qb[0][kc], st[0], 0, 0, 0);
            st[1] = __builtin_amdgcn_mfma_f32_32x32x16_bf16(kf[1][kc], qb[0][kc], st[1], 0, 0, 0);
            st[2] = __builtin_amdgcn_mfma_f32_32x32x16_bf16(kf[0][kc], qb[1][kc], st[2], 0, 0, 0);
            st[3] = __builtin_amdgcn_mfma_f32_32x32x16_bf16(kf[1][kc], qb[1][kc], st[3], 0, 0, 0);
        }

        // per i-group: softmax -> pfrag -> PV (ig0 softmax overlaps ig1 S^T MFMAs)
        #pragma unroll
        for (int ig = 0; ig < 2; ++ig) {
            f32x16 sA = st[ig * 2], sB = st[ig * 2 + 1];
            float mx = sA[0];
            #pragma unroll
            for (int q = 1; q < 16; ++q) mx = fmaxf(mx, sA[q]);
            #pragma unroll
            for (int q = 0; q < 16; ++q) mx = fmaxf(mx, sB[q]);
            mx = fmaxf(mx, __shfl_xor(mx, 32));
            if (__any(mx > mr[ig])) {          // wave-uniform rescale, usually skipped
                float mn = fmaxf(mr[ig], mx);
                float alpha = __builtin_amdgcn_exp2f(mr[ig] - mn);
                mr[ig] = mn;
                lr[ig] *= alpha;
                #pragma unroll
                for (int ct = 0; ct < 4; ++ct)
                    #pragma unroll
                    for (int q = 0; q < 16; ++q) acc[ig][ct][q] *= alpha;
            }
            float mc = mr[ig] - 0.0028150156f;  // centers pkbf truncation
            float p0[16], p1[16], rs = 0.f;
            #pragma unroll
            for (int q = 0; q < 16; ++q) {
                p0[q] = __builtin_amdgcn_exp2f(sA[q] - mc);
                p1[q] = __builtin_amdgcn_exp2f(sB[q] - mc);
                rs += p0[q] + p1[q];
            }
            rs += __shfl_xor(rs, 32);
            lr[ig] += rs;

            // P^T B-frags via half-wave exchange (HW-verified in R3)
            bf16x8 pfrag[4];
            #pragma unroll
            for (int hf = 0; hf < 2; ++hf) {
                const float* pp = hf ? p1 : p0;
                #pragma unroll
                for (int c2 = 0; c2 < 2; ++c2) {
                    int rb = c2 * 8;
                    unsigned int A0 = pkbf(pp[rb + 1], pp[rb + 0]);
                    unsigned int A1 = pkbf(pp[rb + 3], pp[rb + 2]);
                    unsigned int B0 = pkbf(pp[rb + 5], pp[rb + 4]);
                    unsigned int B1 = pkbf(pp[rb + 7], pp[rb + 6]);
                    unsigned int s0 = h ? A0 : B0, s1 = h ? A1 : B1;
                    unsigned int r0 = __shfl_xor(s0, 32), r1 = __shfl_xor(s1, 32);
                    u32x4 f;
                    f[0] = h ? r0 : A0; f[1] = h ? r1 : A1;
                    f[2] = h ? B0 : r0; f[3] = h ? B1 : r1;
                    pfrag[hf * 2 + c2] = __builtin_bit_cast(bf16x8, f);
                }
            }

            #pragma unroll
            for (int ct = 0; ct < 4; ++ct)
                #pragma unroll
                for (int kc2 = 0; kc2 < 4; ++kc2)
                    acc[ig][ct] = __builtin_amdgcn_mfma_f32_32x32x16_bf16(vf[ct][kc2], pfrag[kc2],
                                                                          acc[ig][ct], 0, 0, 0);
        }
    }

    #pragma unroll
    for (int ig = 0; ig < 2; ++ig) {
        float inv = __builtin_amdgcn_rcpf(lr[ig]);
        unsigned short* orow = &oT[((size_t)b * NPOS + iw + ig * 32 + il) * NC];
        #pragma unroll
        for (int ct = 0; ct < 4; ++ct)
            #pragma unroll
            for (int q = 0; q < 16; q += 2) {
                int c = ct * 32 + (q & 3) + 8 * (q >> 2) + 4 * h;
                *(unsigned int*)&orow[c] = pkbf(acc[ig][ct][q + 1] * inv, acc[ig][ct][q] * inv);
            }
    }
}

// ---------------- K4: out = wf @ o + bf + x  (grid 64 x 16, 256 thr) ----------------
__global__ __launch_bounds__(256) void proj_kernel(
    const unsigned short* __restrict__ oT, const unsigned short* __restrict__ wfb,
    const float* __restrict__ bf_, const float* __restrict__ x, float* __restrict__ out) {
    const int b = blockIdx.y, i0 = blockIdx.x * 64;
    const int t = threadIdx.x, lane = t & 63, w = t >> 6, quad = lane >> 4, li = lane & 15;
    bf16x8 aw[2][4];
    for (int mt = 0; mt < 2; ++mt)
        for (int kc = 0; kc < 4; ++kc)
            aw[mt][kc] = *(const bf16x8*)&wfb[((w * 2 + mt) * 16 + li) * 128 + kc * 32 + quad * 8];
    for (int nt = 0; nt < 4; ++nt) {
        bf16x8 bo[4];
        for (int kc = 0; kc < 4; ++kc)
            bo[kc] = *(const bf16x8*)&oT[((size_t)b * NPOS + i0 + nt * 16 + li) * NC + kc * 32 + quad * 8];
        for (int mt = 0; mt < 2; ++mt) {
            f32x4 d = {0.f, 0.f, 0.f, 0.f};
            for (int kc = 0; kc < 4; ++kc)
                d = __builtin_amdgcn_mfma_f32_16x16x32_bf16(aw[mt][kc], bo[kc], d, 0, 0, 0);
            int o0 = (w * 2 + mt) * 16 + quad * 4;
            for (int rr = 0; rr < 4; ++rr) {
                size_t idx = ((size_t)(b * NC + o0 + rr)) * NPOS + i0 + nt * 16 + li;
                out[idx] = d[rr] + bf_[o0 + rr] + x[idx];
            }
        }
    }
}

extern "C" void kernel_launch(void* const* d_in, const int* in_sizes, int n_in,
                              void* d_out, int out_size, void* d_ws, size_t ws_size,
                              hipStream_t stream) {
    const float* x   = (const float*)d_in[0];
    const float* gnw = (const float*)d_in[1];
    const float* gnb = (const float*)d_in[2];
    const float* wq  = (const float*)d_in[3];
    const float* bq  = (const float*)d_in[4];
    const float* wk  = (const float*)d_in[5];
    const float* bk  = (const float*)d_in[6];
    const float* wv  = (const float*)d_in[7];
    const float* bv  = (const float*)d_in[8];
    const float* wf  = (const float*)d_in[9];
    const float* bf_ = (const float*)d_in[10];
    float* out = (float*)d_out;

    char* ws = (char*)d_ws;
    float* mean = (float*)(ws + 0);
    float* rstd = (float*)(ws + 512);
    unsigned short* wqb = (unsigned short*)(ws + 1024);
    unsigned short* wkb = wqb + 16384;
    unsigned short* wvb = wkb + 16384;
    unsigned short* wfb = wvb + 16384;
    unsigned short* qT  = (unsigned short*)(ws + 132096);          // [b][n][c] bf16 (SCF-scaled)
    unsigned short* Kf  = qT + (size_t)NB * NPOS * NC;             // frag-linear K
    unsigned short* Vf  = Kf + (size_t)NB * NPOS * NC;             // frag-linear V
    unsigned short* oT  = Vf + (size_t)NB * NPOS * NC;             // [b][n][c]

    wconv_kernel<<<64, 256, 0, stream>>>(wq, wk, wv, wf, wqb, wkb, wvb, wfb);
    gnstat_kernel<<<128, 256, 0, stream>>>(x, mean, rstd);
    dim3 g(64, 16);
    qkv_kernel<<<g, 256, 0, stream>>>(x, gnw, gnb, mean, rstd, wqb, wkb, wvb, bq, bk, bv, qT, Kf, Vf);
    flash_kernel<<<512, 128, 0, stream>>>(qT, Kf, Vf, oT);
    proj_kernel<<<g, 256, 0, stream>>>(oT, wfb, bf_, x, out);
}

// Round 7
// 343.755 us; speedup vs baseline: 1.2788x; 1.1771x over previous
//
#include <hip/hip_runtime.h>

// Problem constants: b=16, c=128, groups=8, h=w=64 -> n=4096
#define NB   16
#define NC   128
#define NPOS 4096

typedef short bf16x8 __attribute__((ext_vector_type(8)));   // 8 bf16 (4 VGPRs)
typedef float f32x4  __attribute__((ext_vector_type(4)));
typedef float f32x16 __attribute__((ext_vector_type(16)));
typedef unsigned int u32x4 __attribute__((ext_vector_type(4)));

// softmax scale folded into q at QKV time: log2(e)/sqrt(128)
#define SCF 0.12751743075095855f

static __device__ __forceinline__ unsigned short f2bf(float f) {
    unsigned int u = __builtin_bit_cast(unsigned int, f);
    u += 0x7FFFu + ((u >> 16) & 1u);   // round-to-nearest-even
    return (unsigned short)(u >> 16);
}

// pack two floats -> bf16x2 dword (truncating; exp2-arg pre-biased to center)
static __device__ __forceinline__ unsigned int pkbf(float hi, float lo) {
    return __builtin_amdgcn_perm(__builtin_bit_cast(unsigned int, hi),
                                 __builtin_bit_cast(unsigned int, lo), 0x07060302u);
}

// ---------------- K0: fp32 -> bf16 weight conversion (64 blocks x 256) ----------------
__global__ void wconv_kernel(const float* __restrict__ wq, const float* __restrict__ wk,
                             const float* __restrict__ wv, const float* __restrict__ wf,
                             unsigned short* __restrict__ oq, unsigned short* __restrict__ ok,
                             unsigned short* __restrict__ ov, unsigned short* __restrict__ of) {
    int i = blockIdx.x * 256 + threadIdx.x;
    oq[i] = f2bf(wq[i]); ok[i] = f2bf(wk[i]); ov[i] = f2bf(wv[i]); of[i] = f2bf(wf[i]);
}

// ---------------- K1: GroupNorm stats, one block per (b,g), 128 blocks ----------------
__global__ void gnstat_kernel(const float* __restrict__ x, float* __restrict__ mean,
                              float* __restrict__ rstd) {
    int bg = blockIdx.x;
    const float* p = x + (size_t)bg * 65536;
    int t = threadIdx.x;
    float s = 0.f, q = 0.f;
    for (int it = 0; it < 64; ++it) {
        f32x4 v = *(const f32x4*)(p + it * 1024 + t * 4);
        s += v[0] + v[1] + v[2] + v[3];
        q += v[0] * v[0] + v[1] * v[1] + v[2] * v[2] + v[3] * v[3];
    }
    for (int m = 1; m < 64; m <<= 1) { s += __shfl_xor(s, m); q += __shfl_xor(q, m); }
    __shared__ float ls[4], lq[4];
    int w = t >> 6;
    if ((t & 63) == 0) { ls[w] = s; lq[w] = q; }
    __syncthreads();
    if (t == 0) {
        s = ls[0] + ls[1] + ls[2] + ls[3];
        q = lq[0] + lq[1] + lq[2] + lq[3];
        float mu  = s * (1.0f / 65536.0f);
        float var = q * (1.0f / 65536.0f) - mu * mu;
        mean[bg] = mu;
        rstd[bg] = rsqrtf(var + 1e-5f);
    }
}

// ---------------- K2: GN-apply + QKV GEMMs (grid 64 x 16, 256 thr) ----------------
// q pre-scaled by SCF. Outputs:
//   qT [b][n][c] row-major
//   Kf frag-linear: [b][jt][jtile*8+kc][lane=h*32+il][e] , elem K[jt*64+jtile*32+il][kc*16+h*8+e]
//   Vf frag-linear: [b][jt][ct*4+kc2][lane=h*32+il][e]   , elem V[c=ct*32+il][jt*64+kc2*16+h*8+e]
__global__ __launch_bounds__(256) void qkv_kernel(
    const float* __restrict__ x, const float* __restrict__ gnw, const float* __restrict__ gnb,
    const float* __restrict__ mean, const float* __restrict__ rstd,
    const unsigned short* __restrict__ wqb, const unsigned short* __restrict__ wkb,
    const unsigned short* __restrict__ wvb,
    const float* __restrict__ bq, const float* __restrict__ bk, const float* __restrict__ bv,
    unsigned short* __restrict__ qT, unsigned short* __restrict__ Kf, unsigned short* __restrict__ Vf) {
    __shared__ __attribute__((aligned(16))) unsigned short xn[64 * 136];  // [i][c], stride 136
    __shared__ __attribute__((aligned(16))) unsigned short bnc[64 * 128]; // bounce (8192 elems)
    const int b = blockIdx.y, i0 = blockIdx.x * 64, jt = blockIdx.x;
    const int t = threadIdx.x;
    {
        int iL = (t & 15) * 4;
        int cb = (t >> 4) * 2;
        for (int cg = 0; cg < 4; ++cg) {
            int c = cg * 32 + cb;
            int g = c >> 4;
            float mu = mean[b * 8 + g], rs = rstd[b * 8 + g];
            float ga0 = gnw[c] * rs,     be0 = gnb[c]     - mu * ga0;
            float ga1 = gnw[c + 1] * rs, be1 = gnb[c + 1] - mu * ga1;
            const float* p0 = x + ((size_t)(b * NC + c)) * NPOS + i0 + iL;
            f32x4 v0 = *(const f32x4*)p0;
            f32x4 v1 = *(const f32x4*)(p0 + NPOS);
            for (int e = 0; e < 4; ++e) {
                unsigned int u = (unsigned)f2bf(v0[e] * ga0 + be0) |
                                 ((unsigned)f2bf(v1[e] * ga1 + be1) << 16);
                *(unsigned int*)&xn[(iL + e) * 136 + c] = u;
            }
        }
    }
    __syncthreads();

    const int lane = t & 63, w = t >> 6, quad = lane >> 4, li = lane & 15;

    bf16x8 ax[4];
    for (int kc = 0; kc < 4; ++kc)
        ax[kc] = *(const bf16x8*)&xn[(w * 16 + li) * 136 + kc * 32 + quad * 8];

    // ---- q and k GEMMs; D[i][o], i = w*16+quad*4+rr, o = nt*16+li
    for (int wt = 0; wt < 2; ++wt) {
        const unsigned short* W = wt ? wkb : wqb;
        const float* bias = wt ? bk : bq;
        const float osc = wt ? 1.0f : SCF;
        for (int nt = 0; nt < 8; ++nt) {
            f32x4 d = {0.f, 0.f, 0.f, 0.f};
            for (int kc = 0; kc < 4; ++kc) {
                bf16x8 bw = *(const bf16x8*)&W[(nt * 16 + li) * 128 + kc * 32 + quad * 8];
                d = __builtin_amdgcn_mfma_f32_16x16x32_bf16(ax[kc], bw, d, 0, 0, 0);
            }
            float bb = bias[nt * 16 + li];
            int o = nt * 16 + li;
            for (int rr = 0; rr < 4; ++rr) {
                int i = w * 16 + quad * 4 + rr;
                bnc[i * 128 + (((o >> 3) ^ (i & 7)) << 3) + (o & 7)] = f2bf((d[rr] + bb) * osc);
            }
        }
        __syncthreads();
        if (wt == 0) {
            unsigned short* dst = qT + ((size_t)b * NPOS + i0) * NC + t * 32;
            int i = t >> 2;
            for (int s = 0; s < 4; ++s) {
                int cc = (t & 3) * 4 + s;
                *(bf16x8*)(dst + s * 8) = *(const bf16x8*)&bnc[i * 128 + ((cc ^ (i & 7)) << 3)];
            }
        } else {
            unsigned short* dst = Kf + ((size_t)(b * 64 + jt)) * 8192 + t * 32;
            int F = t >> 4, jtile = F >> 3, kc = F & 7;
            for (int s = 0; s < 4; ++s) {
                int L = (t * 4 + s) & 63;
                int i = jtile * 32 + (L & 31);
                int cc = kc * 2 + (L >> 5);
                *(bf16x8*)(dst + s * 8) = *(const bf16x8*)&bnc[i * 128 + ((cc ^ (i & 7)) << 3)];
            }
        }
        __syncthreads();
    }

    // ---- v GEMM: D[o=c][i=j], c = (w*2+mt)*16+quad*4+rr, j = nt*16+li
    bf16x8 av[2][4];
    for (int mt = 0; mt < 2; ++mt)
        for (int kc = 0; kc < 4; ++kc)
            av[mt][kc] = *(const bf16x8*)&wvb[((w * 2 + mt) * 16 + li) * 128 + kc * 32 + quad * 8];
    for (int nt = 0; nt < 4; ++nt) {
        bf16x8 bx[4];
        for (int kc = 0; kc < 4; ++kc)
            bx[kc] = *(const bf16x8*)&xn[(nt * 16 + li) * 136 + kc * 32 + quad * 8];
        for (int mt = 0; mt < 2; ++mt) {
            f32x4 d = {0.f, 0.f, 0.f, 0.f};
            for (int kc = 0; kc < 4; ++kc)
                d = __builtin_amdgcn_mfma_f32_16x16x32_bf16(av[mt][kc], bx[kc], d, 0, 0, 0);
            int o0 = (w * 2 + mt) * 16 + quad * 4;
            int j = nt * 16 + li;
            for (int rr = 0; rr < 4; ++rr) {
                int c = o0 + rr;
                bnc[c * 64 + (((j >> 3) ^ (c & 7)) << 3) + (j & 7)] = f2bf(d[rr] + bv[c]);
            }
        }
    }
    __syncthreads();
    {
        unsigned short* dst = Vf + ((size_t)(b * 64 + jt)) * 8192 + t * 32;
        int F = t >> 4, ct = F >> 2, kc2 = F & 3;
        for (int s = 0; s < 4; ++s) {
            int L = (t * 4 + s) & 63;
            int c = ct * 32 + (L & 31);
            int jc = kc2 * 2 + (L >> 5);
            *(bf16x8*)(dst + s * 8) = *(const bf16x8*)&bnc[c * 64 + ((jc ^ (c & 7)) << 3)];
        }
    }
}

// ---------------- flash iteration body (forceinline; kcur/knxt ping-pong in regs) ----------------
static __device__ __forceinline__ void flash_iter(
    bf16x8 (&kcur)[16], bf16x8 (&knxt)[16],
    const unsigned short*& kp, const unsigned short*& vp,
    const bf16x8 (&qb)[2][8], float (&mr)[2], float (&lr)[2],
    f32x16 (&acc)[2][4], const int h) {
    // V demand-load for current tile (first use ~1000 cyc later: latency covered)
    bf16x8 vf[16];
    #pragma unroll
    for (int m = 0; m < 16; ++m) vf[m] = *(const bf16x8*)(vp + m * 512);
    vp += 8192;
    // K prefetch for NEXT tile into the other ping-pong bank (no dependence on compute)
    #pragma unroll
    for (int m = 0; m < 16; ++m) knxt[m] = *(const bf16x8*)(kp + m * 512);
    kp += 8192;

    // S^T: st[ig*2+jti] ; col i = il, rows j = jti*32 + C-rows
    f32x16 st[4];
    #pragma unroll
    for (int u = 0; u < 4; ++u)
        #pragma unroll
        for (int q = 0; q < 16; ++q) st[u][q] = 0.f;
    #pragma unroll
    for (int kc = 0; kc < 8; ++kc) {
        st[0] = __builtin_amdgcn_mfma_f32_32x32x16_bf16(kcur[kc],     qb[0][kc], st[0], 0, 0, 0);
        st[1] = __builtin_amdgcn_mfma_f32_32x32x16_bf16(kcur[8 + kc], qb[0][kc], st[1], 0, 0, 0);
        st[2] = __builtin_amdgcn_mfma_f32_32x32x16_bf16(kcur[kc],     qb[1][kc], st[2], 0, 0, 0);
        st[3] = __builtin_amdgcn_mfma_f32_32x32x16_bf16(kcur[8 + kc], qb[1][kc], st[3], 0, 0, 0);
    }

    #pragma unroll
    for (int ig = 0; ig < 2; ++ig) {
        float mx = st[ig * 2][0];
        #pragma unroll
        for (int q = 1; q < 16; ++q) mx = fmaxf(mx, st[ig * 2][q]);
        #pragma unroll
        for (int q = 0; q < 16; ++q) mx = fmaxf(mx, st[ig * 2 + 1][q]);
        mx = fmaxf(mx, __shfl_xor(mx, 32));
        if (__any(mx > mr[ig])) {          // wave-uniform rescale, usually skipped
            float mn = fmaxf(mr[ig], mx);
            float alpha = __builtin_amdgcn_exp2f(mr[ig] - mn);
            mr[ig] = mn;
            lr[ig] *= alpha;
            #pragma unroll
            for (int ct = 0; ct < 4; ++ct)
                #pragma unroll
                for (int q = 0; q < 16; ++q) acc[ig][ct][q] *= alpha;
        }
        float mc = mr[ig] - 0.0028150156f;  // centers pkbf truncation
        float p0[16], p1[16], rs = 0.f;
        #pragma unroll
        for (int q = 0; q < 16; ++q) {
            p0[q] = __builtin_amdgcn_exp2f(st[ig * 2][q] - mc);
            p1[q] = __builtin_amdgcn_exp2f(st[ig * 2 + 1][q] - mc);
            rs += p0[q] + p1[q];
        }
        rs += __shfl_xor(rs, 32);
        lr[ig] += rs;

        // P^T B-frags via half-wave exchange (HW-verified R3/R6)
        bf16x8 pfrag[4];
        #pragma unroll
        for (int hf = 0; hf < 2; ++hf) {
            const float* pp = hf ? p1 : p0;
            #pragma unroll
            for (int c2 = 0; c2 < 2; ++c2) {
                int rb = c2 * 8;
                unsigned int A0 = pkbf(pp[rb + 1], pp[rb + 0]);
                unsigned int A1 = pkbf(pp[rb + 3], pp[rb + 2]);
                unsigned int B0 = pkbf(pp[rb + 5], pp[rb + 4]);
                unsigned int B1 = pkbf(pp[rb + 7], pp[rb + 6]);
                unsigned int s0 = h ? A0 : B0, s1 = h ? A1 : B1;
                unsigned int r0 = __shfl_xor(s0, 32), r1 = __shfl_xor(s1, 32);
                u32x4 f;
                f[0] = h ? r0 : A0; f[1] = h ? r1 : A1;
                f[2] = h ? B0 : r0; f[3] = h ? B1 : r1;
                pfrag[hf * 2 + c2] = __builtin_bit_cast(bf16x8, f);
            }
        }

        #pragma unroll
        for (int ct = 0; ct < 4; ++ct)
            #pragma unroll
            for (int kc2 = 0; kc2 < 4; ++kc2)
                acc[ig][ct] = __builtin_amdgcn_mfma_f32_32x32x16_bf16(vf[ct * 4 + kc2], pfrag[kc2],
                                                                      acc[ig][ct], 0, 0, 0);
    }
}

// ---------------- K3: flash attention — barrier-free, LDS-free, K reg-prefetch ----------------
// grid 512 x 128 thr = 2 independent waves/block; each wave: 64 q-rows, all j.
// K frags ping-pong double-buffered in registers (tile jt+1 in flight during jt compute).
__global__ __launch_bounds__(128, 1) void flash_kernel(
    const unsigned short* __restrict__ qT, const unsigned short* __restrict__ Kf,
    const unsigned short* __restrict__ Vf, unsigned short* __restrict__ oT) {
    const int idx = blockIdx.x;
    const int b = (idx & 7) * 2 + ((idx >> 3) & 1);
    const int r = idx >> 4;                       // 0..31
    const int t = threadIdx.x, lane = t & 63, w = t >> 6;
    const int il = lane & 31, h = lane >> 5;
    const int iw = r * 128 + w * 64;              // this wave's 64 q-rows

    bf16x8 qb[2][8];
    #pragma unroll
    for (int ig = 0; ig < 2; ++ig)
        #pragma unroll
        for (int kc = 0; kc < 8; ++kc)
            qb[ig][kc] = *(const bf16x8*)&qT[((size_t)b * NPOS + iw + ig * 32 + il) * NC + kc * 16 + h * 8];

    float mr[2] = {-1e30f, -1e30f}, lr[2] = {0.f, 0.f};
    f32x16 acc[2][4];
    #pragma unroll
    for (int ig = 0; ig < 2; ++ig)
        #pragma unroll
        for (int ct = 0; ct < 4; ++ct)
            #pragma unroll
            for (int q = 0; q < 16; ++q) acc[ig][ct][q] = 0.f;

    const unsigned short* kp = Kf + ((size_t)b * 64) * 8192 + lane * 8;
    const unsigned short* vp = Vf + ((size_t)b * 64) * 8192 + lane * 8;

    bf16x8 kA[16], kB[16];
    #pragma unroll
    for (int m = 0; m < 16; ++m) kA[m] = *(const bf16x8*)(kp + m * 512);   // prologue: tile 0
    kp += 8192;

    // 64 j-tiles, ping-pong unrolled x2. Final prefetch reads one tile past this
    // batch's K region (lands in Vf — valid memory, never used).
    for (int jo = 0; jo < 32; ++jo) {
        flash_iter(kA, kB, kp, vp, qb, mr, lr, acc, h);
        flash_iter(kB, kA, kp, vp, qb, mr, lr, acc, h);
    }

    #pragma unroll
    for (int ig = 0; ig < 2; ++ig) {
        float inv = __builtin_amdgcn_rcpf(lr[ig]);
        unsigned short* orow = &oT[((size_t)b * NPOS + iw + ig * 32 + il) * NC];
        #pragma unroll
        for (int ct = 0; ct < 4; ++ct)
            #pragma unroll
            for (int q = 0; q < 16; q += 2) {
                int c = ct * 32 + (q & 3) + 8 * (q >> 2) + 4 * h;
                *(unsigned int*)&orow[c] = pkbf(acc[ig][ct][q + 1] * inv, acc[ig][ct][q] * inv);
            }
    }
}

// ---------------- K4: out = wf @ o + bf + x  (grid 64 x 16, 256 thr) ----------------
__global__ __launch_bounds__(256) void proj_kernel(
    const unsigned short* __restrict__ oT, const unsigned short* __restrict__ wfb,
    const float* __restrict__ bf_, const float* __restrict__ x, float* __restrict__ out) {
    const int b = blockIdx.y, i0 = blockIdx.x * 64;
    const int t = threadIdx.x, lane = t & 63, w = t >> 6, quad = lane >> 4, li = lane & 15;
    bf16x8 aw[2][4];
    for (int mt = 0; mt < 2; ++mt)
        for (int kc = 0; kc < 4; ++kc)
            aw[mt][kc] = *(const bf16x8*)&wfb[((w * 2 + mt) * 16 + li) * 128 + kc * 32 + quad * 8];
    for (int nt = 0; nt < 4; ++nt) {
        bf16x8 bo[4];
        for (int kc = 0; kc < 4; ++kc)
            bo[kc] = *(const bf16x8*)&oT[((size_t)b * NPOS + i0 + nt * 16 + li) * NC + kc * 32 + quad * 8];
        for (int mt = 0; mt < 2; ++mt) {
            f32x4 d = {0.f, 0.f, 0.f, 0.f};
            for (int kc = 0; kc < 4; ++kc)
                d = __builtin_amdgcn_mfma_f32_16x16x32_bf16(aw[mt][kc], bo[kc], d, 0, 0, 0);
            int o0 = (w * 2 + mt) * 16 + quad * 4;
            for (int rr = 0; rr < 4; ++rr) {
                size_t idx = ((size_t)(b * NC + o0 + rr)) * NPOS + i0 + nt * 16 + li;
                out[idx] = d[rr] + bf_[o0 + rr] + x[idx];
            }
        }
    }
}

extern "C" void kernel_launch(void* const* d_in, const int* in_sizes, int n_in,
                              void* d_out, int out_size, void* d_ws, size_t ws_size,
                              hipStream_t stream) {
    const float* x   = (const float*)d_in[0];
    const float* gnw = (const float*)d_in[1];
    const float* gnb = (const float*)d_in[2];
    const float* wq  = (const float*)d_in[3];
    const float* bq  = (const float*)d_in[4];
    const float* wk  = (const float*)d_in[5];
    const float* bk  = (const float*)d_in[6];
    const float* wv  = (const float*)d_in[7];
    const float* bv  = (const float*)d_in[8];
    const float* wf  = (const float*)d_in[9];
    const float* bf_ = (const float*)d_in[10];
    float* out = (float*)d_out;

    char* ws = (char*)d_ws;
    float* mean = (float*)(ws + 0);
    float* rstd = (float*)(ws + 512);
    unsigned short* wqb = (unsigned short*)(ws + 1024);
    unsigned short* wkb = wqb + 16384;
    unsigned short* wvb = wkb + 16384;
    unsigned short* wfb = wvb + 16384;
    unsigned short* qT  = (unsigned short*)(ws + 132096);          // [b][n][c] bf16 (SCF-scaled)
    unsigned short* Kf  = qT + (size_t)NB * NPOS * NC;             // frag-linear K
    unsigned short* Vf  = Kf + (size_t)NB * NPOS * NC;             // frag-linear V
    unsigned short* oT  = Vf + (size_t)NB * NPOS * NC;             // [b][n][c]

    wconv_kernel<<<64, 256, 0, stream>>>(wq, wk, wv, wf, wqb, wkb, wvb, wfb);
    gnstat_kernel<<<128, 256, 0, stream>>>(x, mean, rstd);
    dim3 g(64, 16);
    qkv_kernel<<<g, 256, 0, stream>>>(x, gnw, gnb, mean, rstd, wqb, wkb, wvb, bq, bk, bv, qT, Kf, Vf);
    flash_kernel<<<512, 128, 0, stream>>>(qT, Kf, Vf, oT);
    proj_kernel<<<g, 256, 0, stream>>>(oT, wfb, bf_, x, out);
}

// Round 8
// 333.684 us; speedup vs baseline: 1.3174x; 1.0302x over previous
//
#include <hip/hip_runtime.h>

// Problem constants: b=16, c=128, groups=8, h=w=64 -> n=4096
#define NB   16
#define NC   128
#define NPOS 4096

typedef short bf16x8 __attribute__((ext_vector_type(8)));   // 8 bf16 (4 VGPRs)
typedef float f32x4  __attribute__((ext_vector_type(4)));
typedef float f32x16 __attribute__((ext_vector_type(16)));
typedef unsigned int u32x4 __attribute__((ext_vector_type(4)));

// softmax scale folded into q at QKV time: log2(e)/sqrt(128)
#define SCF 0.12751743075095855f

static __device__ __forceinline__ unsigned short f2bf(float f) {
    unsigned int u = __builtin_bit_cast(unsigned int, f);
    u += 0x7FFFu + ((u >> 16) & 1u);   // round-to-nearest-even
    return (unsigned short)(u >> 16);
}

// pack two floats -> bf16x2 dword (truncating; callers center via exp2-arg / CP factor)
static __device__ __forceinline__ unsigned int pkbf(float hi, float lo) {
    return __builtin_amdgcn_perm(__builtin_bit_cast(unsigned int, hi),
                                 __builtin_bit_cast(unsigned int, lo), 0x07060302u);
}

static __device__ __forceinline__ float vmax16(const f32x16 v) {
    float a = fmaxf(fmaxf(v[0], v[1]), fmaxf(v[2], v[3]));
    float b = fmaxf(fmaxf(v[4], v[5]), fmaxf(v[6], v[7]));
    float c = fmaxf(fmaxf(v[8], v[9]), fmaxf(v[10], v[11]));
    float d = fmaxf(fmaxf(v[12], v[13]), fmaxf(v[14], v[15]));
    return fmaxf(fmaxf(a, b), fmaxf(c, d));
}

static __device__ __forceinline__ float vsum16(const float* p) {
    float a = (p[0] + p[1]) + (p[2] + p[3]);
    float b = (p[4] + p[5]) + (p[6] + p[7]);
    float c = (p[8] + p[9]) + (p[10] + p[11]);
    float d = (p[12] + p[13]) + (p[14] + p[15]);
    return (a + b) + (c + d);
}

// Build two B-operand frags (chunk parity 0/1) from 16 per-lane floats in C-layout,
// via half-wave exchange: HW-verified in R3/R6/R7.
static __device__ __forceinline__ void mk_bfrag_pair(const float* pp, bf16x8* dst, int h) {
    #pragma unroll
    for (int c2 = 0; c2 < 2; ++c2) {
        int rb = c2 * 8;
        unsigned int A0 = pkbf(pp[rb + 1], pp[rb + 0]);
        unsigned int A1 = pkbf(pp[rb + 3], pp[rb + 2]);
        unsigned int B0 = pkbf(pp[rb + 5], pp[rb + 4]);
        unsigned int B1 = pkbf(pp[rb + 7], pp[rb + 6]);
        unsigned int s0 = h ? A0 : B0, s1 = h ? A1 : B1;   // what partner needs
        unsigned int r0 = __shfl_xor(s0, 32), r1 = __shfl_xor(s1, 32);
        u32x4 f;
        f[0] = h ? r0 : A0; f[1] = h ? r1 : A1;
        f[2] = h ? B0 : r0; f[3] = h ? B1 : r1;
        dst[c2] = __builtin_bit_cast(bf16x8, f);
    }
}

// ---------------- K0: fp32 -> bf16 weight conversion (64 blocks x 256) ----------------
__global__ void wconv_kernel(const float* __restrict__ wq, const float* __restrict__ wk,
                             const float* __restrict__ wv, const float* __restrict__ wf,
                             unsigned short* __restrict__ oq, unsigned short* __restrict__ ok,
                             unsigned short* __restrict__ ov, unsigned short* __restrict__ of) {
    int i = blockIdx.x * 256 + threadIdx.x;
    oq[i] = f2bf(wq[i]); ok[i] = f2bf(wk[i]); ov[i] = f2bf(wv[i]); of[i] = f2bf(wf[i]);
}

// ---------------- K1: GroupNorm stats, one block per (b,g), 128 blocks ----------------
__global__ void gnstat_kernel(const float* __restrict__ x, float* __restrict__ mean,
                              float* __restrict__ rstd) {
    int bg = blockIdx.x;
    const float* p = x + (size_t)bg * 65536;
    int t = threadIdx.x;
    float s = 0.f, q = 0.f;
    for (int it = 0; it < 64; ++it) {
        f32x4 v = *(const f32x4*)(p + it * 1024 + t * 4);
        s += v[0] + v[1] + v[2] + v[3];
        q += v[0] * v[0] + v[1] * v[1] + v[2] * v[2] + v[3] * v[3];
    }
    for (int m = 1; m < 64; m <<= 1) { s += __shfl_xor(s, m); q += __shfl_xor(q, m); }
    __shared__ float ls[4], lq[4];
    int w = t >> 6;
    if ((t & 63) == 0) { ls[w] = s; lq[w] = q; }
    __syncthreads();
    if (t == 0) {
        s = ls[0] + ls[1] + ls[2] + ls[3];
        q = lq[0] + lq[1] + lq[2] + lq[3];
        float mu  = s * (1.0f / 65536.0f);
        float var = q * (1.0f / 65536.0f) - mu * mu;
        mean[bg] = mu;
        rstd[bg] = rsqrtf(var + 1e-5f);
    }
}

// ---------------- K2: GN-apply + QKV GEMMs (grid 64 x 16, 256 thr) ----------------
// q pre-scaled by SCF. Outputs:
//   qT [b][n][c] row-major
//   Kf frag-linear: [b][jt][jtile*8+kc][lane=h*32+il][e] , elem K[jt*64+jtile*32+il][kc*16+h*8+e]
//   Vf frag-linear: [b][jt][ct*4+kc2][lane=h*32+il][e]   , elem V[c=ct*32+il][jt*64+kc2*16+h*8+e]
__global__ __launch_bounds__(256) void qkv_kernel(
    const float* __restrict__ x, const float* __restrict__ gnw, const float* __restrict__ gnb,
    const float* __restrict__ mean, const float* __restrict__ rstd,
    const unsigned short* __restrict__ wqb, const unsigned short* __restrict__ wkb,
    const unsigned short* __restrict__ wvb,
    const float* __restrict__ bq, const float* __restrict__ bk, const float* __restrict__ bv,
    unsigned short* __restrict__ qT, unsigned short* __restrict__ Kf, unsigned short* __restrict__ Vf) {
    __shared__ __attribute__((aligned(16))) unsigned short xn[64 * 136];  // [i][c], stride 136
    __shared__ __attribute__((aligned(16))) unsigned short bnc[64 * 128]; // bounce (8192 elems)
    const int b = blockIdx.y, i0 = blockIdx.x * 64, jt = blockIdx.x;
    const int t = threadIdx.x;
    {
        int iL = (t & 15) * 4;
        int cb = (t >> 4) * 2;
        for (int cg = 0; cg < 4; ++cg) {
            int c = cg * 32 + cb;
            int g = c >> 4;
            float mu = mean[b * 8 + g], rs = rstd[b * 8 + g];
            float ga0 = gnw[c] * rs,     be0 = gnb[c]     - mu * ga0;
            float ga1 = gnw[c + 1] * rs, be1 = gnb[c + 1] - mu * ga1;
            const float* p0 = x + ((size_t)(b * NC + c)) * NPOS + i0 + iL;
            f32x4 v0 = *(const f32x4*)p0;
            f32x4 v1 = *(const f32x4*)(p0 + NPOS);
            for (int e = 0; e < 4; ++e) {
                unsigned int u = (unsigned)f2bf(v0[e] * ga0 + be0) |
                                 ((unsigned)f2bf(v1[e] * ga1 + be1) << 16);
                *(unsigned int*)&xn[(iL + e) * 136 + c] = u;
            }
        }
    }
    __syncthreads();

    const int lane = t & 63, w = t >> 6, quad = lane >> 4, li = lane & 15;

    bf16x8 ax[4];
    for (int kc = 0; kc < 4; ++kc)
        ax[kc] = *(const bf16x8*)&xn[(w * 16 + li) * 136 + kc * 32 + quad * 8];

    // ---- q and k GEMMs; D[i][o], i = w*16+quad*4+rr, o = nt*16+li
    for (int wt = 0; wt < 2; ++wt) {
        const unsigned short* W = wt ? wkb : wqb;
        const float* bias = wt ? bk : bq;
        const float osc = wt ? 1.0f : SCF;
        for (int nt = 0; nt < 8; ++nt) {
            f32x4 d = {0.f, 0.f, 0.f, 0.f};
            for (int kc = 0; kc < 4; ++kc) {
                bf16x8 bw = *(const bf16x8*)&W[(nt * 16 + li) * 128 + kc * 32 + quad * 8];
                d = __builtin_amdgcn_mfma_f32_16x16x32_bf16(ax[kc], bw, d, 0, 0, 0);
            }
            float bb = bias[nt * 16 + li];
            int o = nt * 16 + li;
            for (int rr = 0; rr < 4; ++rr) {
                int i = w * 16 + quad * 4 + rr;
                bnc[i * 128 + (((o >> 3) ^ (i & 7)) << 3) + (o & 7)] = f2bf((d[rr] + bb) * osc);
            }
        }
        __syncthreads();
        if (wt == 0) {
            unsigned short* dst = qT + ((size_t)b * NPOS + i0) * NC + t * 32;
            int i = t >> 2;
            for (int s = 0; s < 4; ++s) {
                int cc = (t & 3) * 4 + s;
                *(bf16x8*)(dst + s * 8) = *(const bf16x8*)&bnc[i * 128 + ((cc ^ (i & 7)) << 3)];
            }
        } else {
            unsigned short* dst = Kf + ((size_t)(b * 64 + jt)) * 8192 + t * 32;
            int F = t >> 4, jtile = F >> 3, kc = F & 7;
            for (int s = 0; s < 4; ++s) {
                int L = (t * 4 + s) & 63;
                int i = jtile * 32 + (L & 31);
                int cc = kc * 2 + (L >> 5);
                *(bf16x8*)(dst + s * 8) = *(const bf16x8*)&bnc[i * 128 + ((cc ^ (i & 7)) << 3)];
            }
        }
        __syncthreads();
    }

    // ---- v GEMM: D[o=c][i=j], c = (w*2+mt)*16+quad*4+rr, j = nt*16+li
    bf16x8 av[2][4];
    for (int mt = 0; mt < 2; ++mt)
        for (int kc = 0; kc < 4; ++kc)
            av[mt][kc] = *(const bf16x8*)&wvb[((w * 2 + mt) * 16 + li) * 128 + kc * 32 + quad * 8];
    for (int nt = 0; nt < 4; ++nt) {
        bf16x8 bx[4];
        for (int kc = 0; kc < 4; ++kc)
            bx[kc] = *(const bf16x8*)&xn[(nt * 16 + li) * 136 + kc * 32 + quad * 8];
        for (int mt = 0; mt < 2; ++mt) {
            f32x4 d = {0.f, 0.f, 0.f, 0.f};
            for (int kc = 0; kc < 4; ++kc)
                d = __builtin_amdgcn_mfma_f32_16x16x32_bf16(av[mt][kc], bx[kc], d, 0, 0, 0);
            int o0 = (w * 2 + mt) * 16 + quad * 4;
            int j = nt * 16 + li;
            for (int rr = 0; rr < 4; ++rr) {
                int c = o0 + rr;
                bnc[c * 64 + (((j >> 3) ^ (c & 7)) << 3) + (j & 7)] = f2bf(d[rr] + bv[c]);
            }
        }
    }
    __syncthreads();
    {
        unsigned short* dst = Vf + ((size_t)(b * 64 + jt)) * 8192 + t * 32;
        int F = t >> 4, ct = F >> 2, kc2 = F & 3;
        for (int s = 0; s < 4; ++s) {
            int L = (t * 4 + s) & 63;
            int c = ct * 32 + (L & 31);
            int jc = kc2 * 2 + (L >> 5);
            *(bf16x8*)(dst + s * 8) = *(const bf16x8*)&bnc[c * 64 + ((jc ^ (c & 7)) << 3)];
        }
    }
}

// ---------------- flash iteration body (forceinline; kcur/knxt ping-pong in regs) ----------------
static __device__ __forceinline__ void flash_iter(
    bf16x8 (&kcur)[16], bf16x8 (&knxt)[16],
    const unsigned short*& kp, const unsigned short*& vp,
    const bf16x8 (&qb)[2][8], float (&mr)[2], float (&lr)[2],
    f32x16 (&acc)[2][4], const int h) {
    // V demand-load for current tile (first use ~1000 cyc later: latency covered)
    bf16x8 vf[16];
    #pragma unroll
    for (int m = 0; m < 16; ++m) vf[m] = *(const bf16x8*)(vp + m * 512);
    vp += 8192;
    // K prefetch for NEXT tile into the other ping-pong bank (no dependence on compute)
    #pragma unroll
    for (int m = 0; m < 16; ++m) knxt[m] = *(const bf16x8*)(kp + m * 512);
    kp += 8192;

    // S^T: st[ig*2+jti] ; col i = il, rows j = jti*32 + C-rows
    f32x16 st[4];
    #pragma unroll
    for (int u = 0; u < 4; ++u)
        #pragma unroll
        for (int q = 0; q < 16; ++q) st[u][q] = 0.f;
    #pragma unroll
    for (int kc = 0; kc < 8; ++kc) {
        st[0] = __builtin_amdgcn_mfma_f32_32x32x16_bf16(kcur[kc],     qb[0][kc], st[0], 0, 0, 0);
        st[1] = __builtin_amdgcn_mfma_f32_32x32x16_bf16(kcur[8 + kc], qb[0][kc], st[1], 0, 0, 0);
        st[2] = __builtin_amdgcn_mfma_f32_32x32x16_bf16(kcur[kc],     qb[1][kc], st[2], 0, 0, 0);
        st[3] = __builtin_amdgcn_mfma_f32_32x32x16_bf16(kcur[8 + kc], qb[1][kc], st[3], 0, 0, 0);
    }

    #pragma unroll
    for (int ig = 0; ig < 2; ++ig) {
        float mx = fmaxf(vmax16(st[ig * 2]), vmax16(st[ig * 2 + 1]));   // depth-5 tree
        mx = fmaxf(mx, __shfl_xor(mx, 32));
        if (__any(mx > mr[ig])) {          // wave-uniform rescale, usually skipped
            float mn = fmaxf(mr[ig], mx);
            float alpha = __builtin_amdgcn_exp2f(mr[ig] - mn);
            mr[ig] = mn;
            lr[ig] *= alpha;
            #pragma unroll
            for (int ct = 0; ct < 4; ++ct)
                #pragma unroll
                for (int q = 0; q < 16; ++q) acc[ig][ct][q] *= alpha;
        }
        float mc = mr[ig] - 0.0028150156f;  // centers pkbf truncation
        float p0[16], p1[16];
        #pragma unroll
        for (int q = 0; q < 16; ++q) {
            p0[q] = __builtin_amdgcn_exp2f(st[ig * 2][q] - mc);
            p1[q] = __builtin_amdgcn_exp2f(st[ig * 2 + 1][q] - mc);
        }
        float rs = vsum16(p0) + vsum16(p1);  // depth-6 tree
        rs += __shfl_xor(rs, 32);
        lr[ig] += rs;

        bf16x8 pfrag[4];
        mk_bfrag_pair(p0, &pfrag[0], h);
        mk_bfrag_pair(p1, &pfrag[2], h);

        #pragma unroll
        for (int ct = 0; ct < 4; ++ct)
            #pragma unroll
            for (int kc2 = 0; kc2 < 4; ++kc2)
                acc[ig][ct] = __builtin_amdgcn_mfma_f32_32x32x16_bf16(vf[ct * 4 + kc2], pfrag[kc2],
                                                                      acc[ig][ct], 0, 0, 0);
    }
}

// ---------------- K3: flash attention + fused output projection + residual ----------------
// grid 512 x 128 thr = 2 independent waves/block; each wave: 64 q-rows, all j.
// K frags ping-pong double-buffered in registers. Epilogue: O^T (C-layout regs) ->
// bf16 B-frags via half-wave exchange -> wf MFMA -> + bias + x residual -> fp32 out.
__global__ __launch_bounds__(128, 1) void flash_kernel(
    const unsigned short* __restrict__ qT, const unsigned short* __restrict__ Kf,
    const unsigned short* __restrict__ Vf, const unsigned short* __restrict__ wfb,
    const float* __restrict__ bf_, const float* __restrict__ x, float* __restrict__ out) {
    const int idx = blockIdx.x;
    const int b = (idx & 7) * 2 + ((idx >> 3) & 1);
    const int r = idx >> 4;                       // 0..31
    const int t = threadIdx.x, lane = t & 63, w = t >> 6;
    const int il = lane & 31, h = lane >> 5;
    const int iw = r * 128 + w * 64;              // this wave's 64 q-rows

    bf16x8 qb[2][8];
    #pragma unroll
    for (int ig = 0; ig < 2; ++ig)
        #pragma unroll
        for (int kc = 0; kc < 8; ++kc)
            qb[ig][kc] = *(const bf16x8*)&qT[((size_t)b * NPOS + iw + ig * 32 + il) * NC + kc * 16 + h * 8];

    float mr[2] = {-1e30f, -1e30f}, lr[2] = {0.f, 0.f};
    f32x16 acc[2][4];
    #pragma unroll
    for (int ig = 0; ig < 2; ++ig)
        #pragma unroll
        for (int ct = 0; ct < 4; ++ct)
            #pragma unroll
            for (int q = 0; q < 16; ++q) acc[ig][ct][q] = 0.f;

    const unsigned short* kp = Kf + ((size_t)b * 64) * 8192 + lane * 8;
    const unsigned short* vp = Vf + ((size_t)b * 64) * 8192 + lane * 8;

    bf16x8 kA[16], kB[16];
    #pragma unroll
    for (int m = 0; m < 16; ++m) kA[m] = *(const bf16x8*)(kp + m * 512);   // prologue: tile 0
    kp += 8192;

    // 64 j-tiles, ping-pong unrolled x2. Final prefetch reads one tile past this
    // batch's K region (lands in Vf — valid memory, never used).
    for (int jo = 0; jo < 32; ++jo) {
        flash_iter(kA, kB, kp, vp, qb, mr, lr, acc, h);
        flash_iter(kB, kA, kp, vp, qb, mr, lr, acc, h);
    }

    // ---- Epilogue: normalize O, convert to B-frags, proj with wf, +bias +x, store fp32
    // obf[ig][kc]: B-frag of O^T for c-chunk kc (c = kc*16 + h*8 + e), col i = il.
    bf16x8 obf[2][8];
    #pragma unroll
    for (int ig = 0; ig < 2; ++ig) {
        float inv = __builtin_amdgcn_rcpf(lr[ig]) * 1.001953125f;  // centers pkbf truncation
        #pragma unroll
        for (int ct = 0; ct < 4; ++ct) {
            float pp[16];
            #pragma unroll
            for (int q = 0; q < 16; ++q) pp[q] = acc[ig][ct][q] * inv;
            mk_bfrag_pair(pp, &obf[ig][ct * 2], h);
        }
    }

    #pragma unroll
    for (int ot = 0; ot < 4; ++ot) {
        bf16x8 wfA[8];
        #pragma unroll
        for (int kc = 0; kc < 8; ++kc)
            wfA[kc] = *(const bf16x8*)&wfb[(ot * 32 + il) * 128 + kc * 16 + h * 8];
        #pragma unroll
        for (int ig = 0; ig < 2; ++ig) {
            f32x16 d;
            #pragma unroll
            for (int q = 0; q < 16; ++q) d[q] = 0.f;
            #pragma unroll
            for (int kc = 0; kc < 8; ++kc)
                d = __builtin_amdgcn_mfma_f32_32x32x16_bf16(wfA[kc], obf[ig][kc], d, 0, 0, 0);
            const int ig_i = iw + ig * 32 + il;
            #pragma unroll
            for (int q = 0; q < 16; ++q) {
                int o = ot * 32 + (q & 3) + 8 * (q >> 2) + 4 * h;
                size_t a = ((size_t)(b * NC + o)) * NPOS + ig_i;
                out[a] = d[q] + bf_[o] + x[a];
            }
        }
    }
}

extern "C" void kernel_launch(void* const* d_in, const int* in_sizes, int n_in,
                              void* d_out, int out_size, void* d_ws, size_t ws_size,
                              hipStream_t stream) {
    const float* x   = (const float*)d_in[0];
    const float* gnw = (const float*)d_in[1];
    const float* gnb = (const float*)d_in[2];
    const float* wq  = (const float*)d_in[3];
    const float* bq  = (const float*)d_in[4];
    const float* wk  = (const float*)d_in[5];
    const float* bk  = (const float*)d_in[6];
    const float* wv  = (const float*)d_in[7];
    const float* bv  = (const float*)d_in[8];
    const float* wf  = (const float*)d_in[9];
    const float* bf_ = (const float*)d_in[10];
    float* out = (float*)d_out;

    char* ws = (char*)d_ws;
    float* mean = (float*)(ws + 0);
    float* rstd = (float*)(ws + 512);
    unsigned short* wqb = (unsigned short*)(ws + 1024);
    unsigned short* wkb = wqb + 16384;
    unsigned short* wvb = wkb + 16384;
    unsigned short* wfb = wvb + 16384;
    unsigned short* qT  = (unsigned short*)(ws + 132096);          // [b][n][c] bf16 (SCF-scaled)
    unsigned short* Kf  = qT + (size_t)NB * NPOS * NC;             // frag-linear K
    unsigned short* Vf  = Kf + (size_t)NB * NPOS * NC;             // frag-linear V

    wconv_kernel<<<64, 256, 0, stream>>>(wq, wk, wv, wf, wqb, wkb, wvb, wfb);
    gnstat_kernel<<<128, 256, 0, stream>>>(x, mean, rstd);
    dim3 g(64, 16);
    qkv_kernel<<<g, 256, 0, stream>>>(x, gnw, gnb, mean, rstd, wqb, wkb, wvb, bq, bk, bv, qT, Kf, Vf);
    flash_kernel<<<512, 128, 0, stream>>>(qT, Kf, Vf, wfb, bf_, x, out);
}